// Round 12
// baseline (90.959 us; speedup 1.0000x reference)
//
#include <hip/hip_runtime.h>
#include <math.h>

// GlobalTransformer: B=2, T=16, N=256 (S=4096), H=64, NHEAD=4, dh=16, L=2
// Round 12: attn0 + all setup folded INTO fused0 (self-sufficient blocks:
// in-block rank-1 score tables, key staging, global-M softmax scan, and
// in-register weight transpose+split for the MFMA phases).
// attn1 / fused1 identical to round 11. 3 dispatches.

namespace {
constexpr int T_ = 16, N_ = 256, S_ = 4096;

// ws float offsets
constexpr size_t OFF_X    = 5632;     // [B*S][64] (t=15 rows only)
constexpr size_t OFF_QKV  = 529920;   // [B*S][192]
constexpr size_t OFF_PM1  = 3675648;  // [128][256]
constexpr size_t OFF_PL1  = 3708416;  // [128][256]
constexpr size_t OFF_PA1  = 3741184;  // [128][256][16]

typedef float  f32x16 __attribute__((ext_vector_type(16)));
typedef short  short8 __attribute__((ext_vector_type(8)));

__device__ inline float wave_sum(float v) {
#pragma unroll
  for (int off = 32; off > 0; off >>= 1) v += __shfl_xor(v, off, 64);
  return v;
}
__device__ inline unsigned bf16_rne(float f) {
  unsigned u = __float_as_uint(f);
  return (u + 0x7FFFu + ((u >> 16) & 1u)) >> 16;
}
__device__ inline unsigned pack2(float a, float b) {   // low<-a, high<-b
  return bf16_rne(a) | (bf16_rne(b) << 16);
}
__device__ inline f32x16 zero16() {
  f32x16 z;
#pragma unroll
  for (int i = 0; i < 16; ++i) z[i] = 0.f;
  return z;
}
__device__ inline float pe_val(int t, int h) {
  float div = __expf((float)(h & ~1) * (-0.14391156831212787f));
  float arg = (float)t * div;
  return (h & 1) ? cosf(arg) : sinf(arg);
}
__device__ inline float rebuild(short h, short l) {
  return __uint_as_float(((unsigned)(unsigned short)h) << 16) +
         __uint_as_float(((unsigned)(unsigned short)l) << 16);
}
__device__ __forceinline__ void split4_store(short* hp, short* lp,
                                             float v0, float v1, float v2, float v3) {
  unsigned u0 = __float_as_uint(v0), u1 = __float_as_uint(v1);
  unsigned u2 = __float_as_uint(v2), u3 = __float_as_uint(v3);
  float r0 = v0 - __uint_as_float(u0 & 0xFFFF0000u);
  float r1 = v1 - __uint_as_float(u1 & 0xFFFF0000u);
  float r2 = v2 - __uint_as_float(u2 & 0xFFFF0000u);
  float r3 = v3 - __uint_as_float(u3 & 0xFFFF0000u);
  *(uint2*)hp = make_uint2((u0 >> 16) | (u1 & 0xFFFF0000u),
                           (u2 >> 16) | (u3 & 0xFFFF0000u));
  *(uint2*)lp = make_uint2(pack2(r0, r1), pack2(r2, r3));
}
// Y^T tile GEMM, weights loaded fp32 from global (coalesced across lanes),
// hi/lo-split in-register. W layout [in][out]; A-value = W[k][tileBase+l31].
__device__ __forceinline__ f32x16 gemm_tile_g(
    const float* __restrict__ W, int outDim, int tileBase, int nkt,
    const short* Bh, const short* Bl, int bstride, int l31, int hi) {
  f32x16 C = zero16();
  int colr = tileBase + l31;
  for (int kt = 0; kt < nkt; ++kt) {
    int ko = kt * 16 + 8 * hi;
    short8 Ah, Al;
#pragma unroll
    for (int e = 0; e < 8; ++e) {
      float v = W[(ko + e) * outDim + colr];
      unsigned u = __float_as_uint(v);
      Ah[e] = (short)(u >> 16);
      Al[e] = (short)bf16_rne(v - __uint_as_float(u & 0xFFFF0000u));
    }
    short8 Bh8 = *(const short8*)&Bh[l31 * bstride + ko];
    short8 Bl8 = *(const short8*)&Bl[l31 * bstride + ko];
    C = __builtin_amdgcn_mfma_f32_32x32x16_bf16(Ah, Bh8, C, 0, 0, 0);
    C = __builtin_amdgcn_mfma_f32_32x32x16_bf16(Al, Bh8, C, 0, 0, 0);
    C = __builtin_amdgcn_mfma_f32_32x32x16_bf16(Ah, Bl8, C, 0, 0, 0);
  }
  return C;
}

// -------- fused0: self-sufficient layer-0 block + qkv(layer1) --------------
// 512 blocks (b, t desc, 16 rows) x 256 threads (4 waves), 2 blocks/CU.
__global__ __launch_bounds__(256, 2) void k_fused0(
    const float* __restrict__ x_seq, const float* __restrict__ Wi,
    const float* __restrict__ bi, const float* __restrict__ Wqkv,
    const float* __restrict__ bqkv,
    const float* __restrict__ Wo, const float* __restrict__ bo,
    const float* __restrict__ g1, const float* __restrict__ be1,
    const float* __restrict__ W1, const float* __restrict__ bb1,
    const float* __restrict__ W2, const float* __restrict__ bb2,
    const float* __restrict__ g2, const float* __restrict__ be2,
    float* __restrict__ X, float* __restrict__ QKV) {
  __shared__ __align__(16) char smem[56576];
  short (*qbh)[72]  = (short(*)[72])(smem + 0);
  short (*qbl)[72]  = (short(*)[72])(smem + 4608);
  short (*xsh)[72]  = (short(*)[72])(smem + 9216);
  short (*xsl)[72]  = (short(*)[72])(smem + 13824);
  short (*hsh)[264] = (short(*)[264])(smem + 18432);
  short (*hsl)[264] = (short(*)[264])(smem + 35328);
  float (*ys)[68]   = (float(*)[68])(smem + 52224);
  // phase-A overlays (dead before the regions' later uses)
  float (*keys)[256] = (float(*)[256])(smem + 18432);   // 16KB on hsh
  float (*pek)[64]   = (float(*)[64])(smem + 52224);    // 4KB on ys
  float (*Btv)[64]   = (float(*)[64])(smem + 35328);    // 4KB on hsl
  float (*Bkk)[64]   = (float(*)[64])(smem + 39424);    // 4KB on hsl
  float* xbv    = (float*)(smem + 43520);  // 64 (survives until LN1)
  float* AqS    = (float*)(smem + 43776);
  float* AkS    = (float*)(smem + 44032);
  float* AvS    = (float*)(smem + 44288);
  float* BqS    = (float*)(smem + 44544);
  float* alphaS = (float*)(smem + 44800);  // 4
  float* gamS   = (float*)(smem + 44816);  // 4
  float* betaS  = (float*)(smem + 44832);  // 64 [h*16+kt]
  float* deltS  = (float*)(smem + 45088);  // 64
  float* mnS    = (float*)(smem + 45344);  // 16
  float* mxS    = (float*)(smem + 45408);  // 16

  const float K2 = 0.36067376022224085f;   // (1/sqrt(16)) * log2(e)
  const float* Wq1 = Wqkv + 64 * 192;
  const float* bq1 = bqkv + 192;

  int blk = blockIdx.x, tid = threadIdx.x;
  int b = blk >> 8, t = 15 - ((blk >> 4) & 15), n0 = (blk & 15) * 16;
  int gbase = b * S_ + t * N_ + n0;
  int w = tid >> 6, lane = tid & 63, l31 = lane & 31, hi = lane >> 5;

  // zero rows 16..31 of qb/xs B-source buffers
  for (int i = tid; i < 16 * 72; i += 256) {
    (&qbh[16][0])[i] = 0; (&qbl[16][0])[i] = 0;
    (&xsh[16][0])[i] = 0; (&xsl[16][0])[i] = 0;
  }
  // pek[kt][hh] = pe(kt, hh)
#pragma unroll
  for (int i = 0; i < 4; ++i) {
    int u = tid + 256 * i;
    pek[u >> 6][u & 63] = pe_val(u >> 6, u & 63);
  }
  __syncthreads();

  // ---- PRE: A-parts, Bq, Bk-parts(kt<=t), keys, xbv ----
  for (int c = tid; c < 192; c += 256) {
    float acc = 0.f;
#pragma unroll 8
    for (int hh = 0; hh < 64; ++hh) acc = fmaf(Wi[hh], Wqkv[hh * 192 + c], acc);
    if (c < 64) AqS[c] = acc;
    else if (c < 128) AkS[c - 64] = acc;
    else AvS[c - 128] = acc;
  }
  if (tid < 64) {
    float acc = bqkv[tid];
#pragma unroll 8
    for (int hh = 0; hh < 64; ++hh)
      acc = fmaf(bi[hh] + pek[t][hh], Wqkv[hh * 192 + tid], acc);
    BqS[tid] = acc;
    xbv[tid] = bi[tid] + pek[t][tid];
  }
  for (int u = tid; u < (t + 1) * 128; u += 256) {
    int kt = u >> 7, cc = u & 127, col = 64 + cc;
    float acc = bqkv[col];
#pragma unroll 8
    for (int hh = 0; hh < 64; ++hh)
      acc = fmaf(bi[hh] + pek[kt][hh], Wqkv[hh * 192 + col], acc);
    if (cc < 64) Bkk[kt][cc] = acc; else Btv[kt][cc - 64] = acc;
  }
  for (int u = tid; u < (t + 1) * 256; u += 256)
    keys[u >> 8][u & 255] = x_seq[(size_t)b * S_ + u];
  __syncthreads();

  // ---- tables: alpha/gam per h; beta/delt per (h,kt); mn/mx per kt ----
  if (tid < 4) {
    float al = 0.f, gm = 0.f;
#pragma unroll
    for (int i = 0; i < 16; ++i) {
      al = fmaf(AqS[tid * 16 + i], AkS[tid * 16 + i], al);
      gm = fmaf(AkS[tid * 16 + i], BqS[tid * 16 + i], gm);
    }
    alphaS[tid] = K2 * al; gamS[tid] = K2 * gm;
  }
  if (tid < 64 && (tid & 15) <= t) {
    int h = tid >> 4, kt = tid & 15;
    float be = 0.f, de = 0.f;
#pragma unroll
    for (int i = 0; i < 16; ++i) {
      float bk = Bkk[kt][h * 16 + i];
      be = fmaf(AqS[h * 16 + i], bk, be);
      de = fmaf(BqS[h * 16 + i], bk, de);
    }
    betaS[h * 16 + kt] = K2 * be; deltS[h * 16 + kt] = K2 * de;
  }
  {
    int kt = tid >> 4, s16 = tid & 15;
    if (kt <= t) {
      float mn = 1e30f, mx = -1e30f;
#pragma unroll
      for (int j = 0; j < 16; ++j) {
        float v = keys[kt][s16 * 16 + j];
        mn = fminf(mn, v); mx = fmaxf(mx, v);
      }
#pragma unroll
      for (int off = 1; off < 16; off <<= 1) {
        mn = fminf(mn, __shfl_xor(mn, off, 64));
        mx = fmaxf(mx, __shfl_xor(mx, off, 64));
      }
      if (s16 == 0) { mnS[kt] = mn; mxS[kt] = mx; }
    }
  }
  __syncthreads();

  // ---- scan: global-M softmax; wave=h, lane = q*4+s (s = key quarter) ----
  {
    int h = w, q = lane >> 2, s = lane & 3;
    float x = keys[t][n0 + q];
    float a = fmaf(alphaS[h], x, gamS[h]);
    float M = -1e30f;
    for (int kt = 0; kt <= t; ++kt) {
      float xe = (a >= 0.f) ? mxS[kt] : mnS[kt];
      float Mg = fmaf(a, xe, fmaf(betaS[h * 16 + kt], x, deltS[h * 16 + kt]));
      M = fmaxf(M, Mg);
    }
    float D = 0.f, SX = 0.f, c0 = 0.f, c1 = 0.f, c2 = 0.f, c3 = 0.f;
    int dbase = h * 16 + s * 4;
    for (int kt = 0; kt <= t; ++kt) {
      float off = fmaf(betaS[h * 16 + kt], x, deltS[h * 16 + kt]) - M;
      const float* kr = &keys[kt][s * 64];
      float spa = 0.f, spb = 0.f;
#pragma unroll 8
      for (int jj = 0; jj < 64; jj += 2) {
        int j0 = (jj + s * 8) & 63, j1 = (jj + 1 + s * 8) & 63;  // bank stagger
        float x0 = kr[j0], x1 = kr[j1];
        float p0 = __builtin_amdgcn_exp2f(fmaf(a, x0, off));
        float p1 = __builtin_amdgcn_exp2f(fmaf(a, x1, off));
        spa += p0; spb += p1;
        SX = fmaf(p0, x0, SX); SX = fmaf(p1, x1, SX);
      }
      float sp = spa + spb;
      sp += __shfl_xor(sp, 1, 64);
      sp += __shfl_xor(sp, 2, 64);
      D += sp;
      c0 = fmaf(sp, Btv[kt][dbase + 0], c0);
      c1 = fmaf(sp, Btv[kt][dbase + 1], c1);
      c2 = fmaf(sp, Btv[kt][dbase + 2], c2);
      c3 = fmaf(sp, Btv[kt][dbase + 3], c3);
    }
    SX += __shfl_xor(SX, 1, 64);
    SX += __shfl_xor(SX, 2, 64);
    float invD = 1.f / D;
    float o0 = fmaf(SX, AvS[dbase + 0], c0) * invD;
    float o1 = fmaf(SX, AvS[dbase + 1], c1) * invD;
    float o2 = fmaf(SX, AvS[dbase + 2], c2) * invD;
    float o3 = fmaf(SX, AvS[dbase + 3], c3) * invD;
    split4_store(&qbh[q][dbase], &qbl[q][dbase], o0, o1, o2, o3);
  }
  __syncthreads();

  // ---- proj (waves 0,1); waves 2,3 re-zero hsh/hsl rows 16..31 ----
  if (w < 2) {
    f32x16 C = gemm_tile_g(Wo, 64, w * 32, 4, &qbh[0][0], &qbl[0][0], 72, l31, hi);
    if (l31 < 16) {
#pragma unroll
      for (int g = 0; g < 4; ++g)
        *(float4*)&ys[l31][w * 32 + g * 8 + 4 * hi] =
            make_float4(C[4 * g], C[4 * g + 1], C[4 * g + 2], C[4 * g + 3]);
    }
  } else {
    for (int i = tid - 128; i < 16 * 264; i += 128) {
      (&hsh[16][0])[i] = 0; (&hsl[16][0])[i] = 0;
    }
  }
  __syncthreads();

  // ---- LN1 ----
  {
    int c = tid & 63, grp = tid >> 6;
    float xb_c = xbv[c], wi_c = Wi[c], bo_c = bo[c];
    float g1c = g1[c], be1c = be1[c];
#pragma unroll
    for (int rr = 0; rr < 4; ++rr) {
      int row = grp * 4 + rr;
      float xv = x_seq[gbase + row];
      float val = ys[row][c] + bo_c + fmaf(xv, wi_c, xb_c);
      float mean = wave_sum(val) * (1.f / 64.f);
      float dv = val - mean;
      float var = wave_sum(dv * dv) * (1.f / 64.f);
      float xn = dv * rsqrtf(var + 1e-5f) * g1c + be1c;
      unsigned u = __float_as_uint(xn);
      xsh[row][c] = (short)(u >> 16);
      xsl[row][c] = (short)bf16_rne(xn - __uint_as_float(u & 0xFFFF0000u));
    }
  }
  __syncthreads();

  // ---- FFN1 ----
#pragma unroll
  for (int ti = 0; ti < 2; ++ti) {
    int tt = w + 4 * ti;
    f32x16 C = gemm_tile_g(W1, 256, tt * 32, 4, &xsh[0][0], &xsl[0][0], 72, l31, hi);
    if (l31 < 16) {
#pragma unroll
      for (int g = 0; g < 4; ++g) {
        int cb = tt * 32 + g * 8 + 4 * hi;
        float v0 = fmaxf(C[4 * g + 0] + bb1[cb + 0], 0.f);
        float v1 = fmaxf(C[4 * g + 1] + bb1[cb + 1], 0.f);
        float v2 = fmaxf(C[4 * g + 2] + bb1[cb + 2], 0.f);
        float v3 = fmaxf(C[4 * g + 3] + bb1[cb + 3], 0.f);
        split4_store(&hsh[l31][cb], &hsl[l31][cb], v0, v1, v2, v3);
      }
    }
  }
  __syncthreads();

  // ---- FFN2 ----
  if (w < 2) {
    f32x16 C = gemm_tile_g(W2, 64, w * 32, 16, &hsh[0][0], &hsl[0][0], 264, l31, hi);
    if (l31 < 16) {
#pragma unroll
      for (int g = 0; g < 4; ++g)
        *(float4*)&ys[l31][w * 32 + g * 8 + 4 * hi] =
            make_float4(C[4 * g], C[4 * g + 1], C[4 * g + 2], C[4 * g + 3]);
    }
  }
  __syncthreads();

  // ---- LN2 ----
  {
    int c = tid & 63, grp = tid >> 6;
    float b2c = bb2[c], g2c = g2[c], be2c = be2[c];
#pragma unroll
    for (int rr = 0; rr < 4; ++rr) {
      int row = grp * 4 + rr;
      float val = ys[row][c] + b2c + rebuild(xsh[row][c], xsl[row][c]);
      float mean = wave_sum(val) * (1.f / 64.f);
      float dv = val - mean;
      float var = wave_sum(dv * dv) * (1.f / 64.f);
      float xn = dv * rsqrtf(var + 1e-5f) * g2c + be2c;
      unsigned u = __float_as_uint(xn);
      qbh[row][c] = (short)(u >> 16);
      qbl[row][c] = (short)bf16_rne(xn - __uint_as_float(u & 0xFFFF0000u));
      if (t == 15) X[(size_t)(gbase + row) * 64 + c] = xn;
    }
  }
  __syncthreads();

  // ---- qkv(layer1): K/V always, Q only for t=15 rows ----
  {
    int tlA = (t == 15) ? w : (2 + w);
    int ntl = (t == 15 && w < 2) ? 2 : 1;
    for (int ti = 0; ti < ntl; ++ti) {
      int tt = ti ? (w + 4) : tlA;
      f32x16 C = gemm_tile_g(Wq1, 192, tt * 32, 4, &qbh[0][0], &qbl[0][0], 72, l31, hi);
      if (l31 < 16) {
        size_t rb = (size_t)(gbase + l31) * 192;
#pragma unroll
        for (int g = 0; g < 4; ++g) {
          int cb = tt * 32 + g * 8 + 4 * hi;
          float4 o = make_float4(C[4 * g + 0] + bq1[cb + 0],
                                 C[4 * g + 1] + bq1[cb + 1],
                                 C[4 * g + 2] + bq1[cb + 2],
                                 C[4 * g + 3] + bq1[cb + 3]);
          *(float4*)&QKV[rb + cb] = o;
        }
      }
    }
  }
}

// -------- layer-1 MFMA flash attention (tq=15 only), round-11 verified -----
__global__ __launch_bounds__(256, 4) void k_attn1(const float* __restrict__ QKV,
    float* __restrict__ PM, float* __restrict__ PL, float* __restrict__ PACC) {
  __shared__ short KH[2][256][8];
  __shared__ short KL[2][256][8];
  __shared__ short VT[32][264];
  int blk = blockIdx.x;
  int bh = blk >> 4, kt = blk & 15;
  const int tq = 15;
  int b = bh >> 2, h = bh & 3;
  int tid = threadIdx.x, w = tid >> 6, lane = tid & 63;
  int l31 = lane & 31, hi = lane >> 5;
  const size_t qkvbase = (size_t)b * S_ * 192;

  for (int i = tid; i < 16 * 264; i += 256) (&VT[16][0])[i] = 0;
  {
    const float* kp = QKV + qkvbase + (size_t)(kt * N_ + tid) * 192 + 64 + h * 16;
    float kf[16], vf[16];
#pragma unroll
    for (int i = 0; i < 4; ++i) {
      float4 k4 = *(const float4*)(kp + 4 * i);
      kf[4 * i] = k4.x; kf[4 * i + 1] = k4.y; kf[4 * i + 2] = k4.z; kf[4 * i + 3] = k4.w;
      float4 v4 = *(const float4*)(kp + 64 + 4 * i);
      vf[4 * i] = v4.x; vf[4 * i + 1] = v4.y; vf[4 * i + 2] = v4.z; vf[4 * i + 3] = v4.w;
    }
    short8 kh0, kh1, kl0, kl1;
#pragma unroll
    for (int i = 0; i < 8; ++i) {
      unsigned ht0 = __float_as_uint(kf[i]) & 0xFFFF0000u;
      kh0[i] = (short)(ht0 >> 16);
      kl0[i] = (short)bf16_rne(kf[i] - __uint_as_float(ht0));
      unsigned ht1 = __float_as_uint(kf[i + 8]) & 0xFFFF0000u;
      kh1[i] = (short)(ht1 >> 16);
      kl1[i] = (short)bf16_rne(kf[i + 8] - __uint_as_float(ht1));
    }
    *(short8*)&KH[0][tid][0] = kh0;
    *(short8*)&KH[1][tid][0] = kh1;
    *(short8*)&KL[0][tid][0] = kl0;
    *(short8*)&KL[1][tid][0] = kl1;
#pragma unroll
    for (int i = 0; i < 16; ++i) VT[i][tid] = (short)bf16_rne(vf[i]);
  }
  __syncthreads();

  const float cscale = 0.36067376022224085f;
  short8 Qh[2], Ql[2];
#pragma unroll
  for (int qs = 0; qs < 2; ++qs) {
    int qloc = w * 64 + qs * 32 + l31;
    const float* qp = QKV + qkvbase + (size_t)(tq * N_ + qloc) * 192 + h * 16 + 8 * hi;
    float4 a4 = *(const float4*)(qp), b4 = *(const float4*)(qp + 4);
    float qf[8] = {a4.x, a4.y, a4.z, a4.w, b4.x, b4.y, b4.z, b4.w};
#pragma unroll
    for (int i = 0; i < 8; ++i) {
      float q = qf[i] * cscale;
      unsigned ht = __float_as_uint(q) & 0xFFFF0000u;
      Qh[qs][i] = (short)(ht >> 16);
      Ql[qs][i] = (short)bf16_rne(q - __uint_as_float(ht));
    }
  }

  f32x16 O0 = zero16(), O1 = zero16();
  float m[2] = {-INFINITY, -INFINITY}, lsum[2] = {0.f, 0.f};

  for (int ks = 0; ks < 8; ++ks) {
    const short8 Kh = *(const short8*)&KH[hi][ks * 32 + l31][0];
    const short8 Kl = *(const short8*)&KL[hi][ks * 32 + l31][0];
    const short8 Va = *(const short8*)&VT[l31][ks * 32 + 8 * hi];
    const short8 Vb = *(const short8*)&VT[l31][ks * 32 + 8 * hi + 16];

#pragma unroll
    for (int qs = 0; qs < 2; ++qs) {
      f32x16 S = zero16();
      S = __builtin_amdgcn_mfma_f32_32x32x16_bf16(Kh, Qh[qs], S, 0, 0, 0);
      S = __builtin_amdgcn_mfma_f32_32x32x16_bf16(Kl, Qh[qs], S, 0, 0, 0);
      S = __builtin_amdgcn_mfma_f32_32x32x16_bf16(Kh, Ql[qs], S, 0, 0, 0);

      float pm = S[0];
#pragma unroll
      for (int r = 1; r < 16; ++r) pm = fmaxf(pm, S[r]);
      pm = fmaxf(pm, __shfl_xor(pm, 32, 64));
      float mq = m[qs];
      if (__any(pm > mq)) {
        float mn = fmaxf(mq, pm);
        float al = __builtin_amdgcn_exp2f(mq - mn);
        m[qs] = mn; mq = mn;
        lsum[qs] *= al;
        if (qs == 0) {
#pragma unroll
          for (int r = 0; r < 16; ++r) O0[r] *= al;
        } else {
#pragma unroll
          for (int r = 0; r < 16; ++r) O1[r] *= al;
        }
      }
      float pr[16], ps = 0.f;
#pragma unroll
      for (int r = 0; r < 16; ++r) {
        pr[r] = __builtin_amdgcn_exp2f(S[r] - mq);
        ps += pr[r];
      }
      lsum[qs] += ps + __shfl_xor(ps, 32, 64);

      unsigned w01 = pack2(pr[0],  pr[1]);
      unsigned w23 = pack2(pr[2],  pr[3]);
      unsigned w45 = pack2(pr[4],  pr[5]);
      unsigned w67 = pack2(pr[6],  pr[7]);
      unsigned w89 = pack2(pr[8],  pr[9]);
      unsigned wab = pack2(pr[10], pr[11]);
      unsigned wcd = pack2(pr[12], pr[13]);
      unsigned wef = pack2(pr[14], pr[15]);
      unsigned e01 = __shfl_xor(w01, 32, 64), e23 = __shfl_xor(w23, 32, 64);
      unsigned e45 = __shfl_xor(w45, 32, 64), e67 = __shfl_xor(w67, 32, 64);
      unsigned e89 = __shfl_xor(w89, 32, 64), eab = __shfl_xor(wab, 32, 64);
      unsigned ecd = __shfl_xor(wcd, 32, 64), eef = __shfl_xor(wef, 32, 64);
      union { short8 s; unsigned u[4]; } P0u, P1u;
      P0u.u[0] = hi ? e45 : w01;
      P0u.u[1] = hi ? e67 : w23;
      P0u.u[2] = hi ? w45 : e01;
      P0u.u[3] = hi ? w67 : e23;
      P1u.u[0] = hi ? ecd : w89;
      P1u.u[1] = hi ? eef : wab;
      P1u.u[2] = hi ? wcd : e89;
      P1u.u[3] = hi ? wef : eab;

      if (qs == 0) {
        O0 = __builtin_amdgcn_mfma_f32_32x32x16_bf16(Va, P0u.s, O0, 0, 0, 0);
        O0 = __builtin_amdgcn_mfma_f32_32x32x16_bf16(Vb, P1u.s, O0, 0, 0, 0);
      } else {
        O1 = __builtin_amdgcn_mfma_f32_32x32x16_bf16(Va, P0u.s, O1, 0, 0, 0);
        O1 = __builtin_amdgcn_mfma_f32_32x32x16_bf16(Vb, P1u.s, O1, 0, 0, 0);
      }
    }
  }

  int slot = blk;
#pragma unroll
  for (int qs = 0; qs < 2; ++qs) {
    int qloc = w * 64 + qs * 32 + l31;
    if (lane < 32) {
      PM[(size_t)slot * 256 + qloc] = m[qs];
      PL[(size_t)slot * 256 + qloc] = lsum[qs];
    }
    float* pa = PACC + (size_t)slot * 4096 + (size_t)qloc * 16;
    float4 lo4, hi4;
    if (qs == 0) {
      lo4 = make_float4(O0[0], O0[1], O0[2], O0[3]);
      hi4 = make_float4(O0[4], O0[5], O0[6], O0[7]);
    } else {
      lo4 = make_float4(O1[0], O1[1], O1[2], O1[3]);
      hi4 = make_float4(O1[4], O1[5], O1[6], O1[7]);
    }
    *(float4*)(pa + 4 * hi)     = lo4;
    *(float4*)(pa + 8 + 4 * hi) = hi4;
  }
}

// -------- fused1: combine + proj + LN1 + FFN + LN2 + head (round 11) -------
__global__ __launch_bounds__(256, 2) void k_fused1(
    const float* __restrict__ PM1, const float* __restrict__ PL1,
    const float* __restrict__ PA1,
    const float* __restrict__ Wo, const float* __restrict__ bo,
    const float* __restrict__ g1, const float* __restrict__ be1,
    const float* __restrict__ W1, const float* __restrict__ bb1,
    const float* __restrict__ W2, const float* __restrict__ bb2,
    const float* __restrict__ g2, const float* __restrict__ be2,
    const float* __restrict__ X,
    const float* __restrict__ dW1, const float* __restrict__ db1,
    const float* __restrict__ dW2, const float* __restrict__ db2,
    const float* __restrict__ dW3, const float* __restrict__ db3,
    float* __restrict__ out) {
  __shared__ float os[4][64], rs[4][64], xs[4][64], x2[4][64], hs[4][256];
  __shared__ float h1s[4][32], h2s[4][16];
  int tid = threadIdx.x;
  int bb = blockIdx.x >> 6;
  int nbase = (blockIdx.x & 63) * 4;
  int row0 = bb * S_ + 15 * N_ + nbase;
  size_t base = (size_t)row0 * 64;

  {
    int d = tid & 15, r = (tid >> 4) & 3, h = tid >> 6;
    int n = nbase + r;
    int sb = (bb * 4 + h) * 16;
    float M = -INFINITY;
#pragma unroll
    for (int s = 0; s < 16; ++s) M = fmaxf(M, PM1[(size_t)(sb + s) * 256 + n]);
    float D = 0.f, od = 0.f;
#pragma unroll
    for (int s = 0; s < 16; ++s) {
      float wgt = __builtin_amdgcn_exp2f(PM1[(size_t)(sb + s) * 256 + n] - M);
      D = fmaf(PL1[(size_t)(sb + s) * 256 + n], wgt, D);
      od = fmaf(PA1[(size_t)(sb + s) * 4096 + (size_t)n * 16 + d], wgt, od);
    }
    os[r][h * 16 + d] = od / D;
    rs[tid >> 6][tid & 63] = X[base + tid];
  }
  __syncthreads();

  int c = tid & 63, grp = tid >> 6;
  {
    float a = bo[c];
#pragma unroll 8
    for (int k = 0; k < 64; ++k) a = fmaf(os[grp][k], Wo[k * 64 + c], a);
    float val = a + rs[grp][c];
    float mean = wave_sum(val) * (1.f / 64.f);
    float dv = val - mean;
    float var = wave_sum(dv * dv) * (1.f / 64.f);
    xs[grp][c] = dv * rsqrtf(var + 1e-5f) * g1[c] + be1[c];
  }
  __syncthreads();

  {
    float am0 = bb1[tid], am1 = am0, am2 = am0, am3 = am0;
    for (int k4 = 0; k4 < 16; ++k4) {
      float w0 = W1[(4 * k4 + 0) * 256 + tid];
      float w1v = W1[(4 * k4 + 1) * 256 + tid];
      float w2v = W1[(4 * k4 + 2) * 256 + tid];
      float w3v = W1[(4 * k4 + 3) * 256 + tid];
      float4 x0 = *(const float4*)&xs[0][4 * k4];
      float4 x1 = *(const float4*)&xs[1][4 * k4];
      float4 x2v = *(const float4*)&xs[2][4 * k4];
      float4 x3 = *(const float4*)&xs[3][4 * k4];
      am0 = fmaf(x0.x, w0, am0); am0 = fmaf(x0.y, w1v, am0);
      am0 = fmaf(x0.z, w2v, am0); am0 = fmaf(x0.w, w3v, am0);
      am1 = fmaf(x1.x, w0, am1); am1 = fmaf(x1.y, w1v, am1);
      am1 = fmaf(x1.z, w2v, am1); am1 = fmaf(x1.w, w3v, am1);
      am2 = fmaf(x2v.x, w0, am2); am2 = fmaf(x2v.y, w1v, am2);
      am2 = fmaf(x2v.z, w2v, am2); am2 = fmaf(x2v.w, w3v, am2);
      am3 = fmaf(x3.x, w0, am3); am3 = fmaf(x3.y, w1v, am3);
      am3 = fmaf(x3.z, w2v, am3); am3 = fmaf(x3.w, w3v, am3);
    }
    hs[0][tid] = fmaxf(am0, 0.f);
    hs[1][tid] = fmaxf(am1, 0.f);
    hs[2][tid] = fmaxf(am2, 0.f);
    hs[3][tid] = fmaxf(am3, 0.f);
  }
  __syncthreads();

  {
    float a = bb2[c];
    for (int k4 = 0; k4 < 64; ++k4) {
      float w0 = W2[(4 * k4 + 0) * 64 + c];
      float w1v = W2[(4 * k4 + 1) * 64 + c];
      float w2v = W2[(4 * k4 + 2) * 64 + c];
      float w3v = W2[(4 * k4 + 3) * 64 + c];
      float4 hv = *(const float4*)&hs[grp][4 * k4];
      a = fmaf(hv.x, w0, a); a = fmaf(hv.y, w1v, a);
      a = fmaf(hv.z, w2v, a); a = fmaf(hv.w, w3v, a);
    }
    float val = a + xs[grp][c];
    float mean = wave_sum(val) * (1.f / 64.f);
    float dv = val - mean;
    float var = wave_sum(dv * dv) * (1.f / 64.f);
    x2[grp][c] = dv * rsqrtf(var + 1e-5f) * g2[c] + be2[c];
  }
  __syncthreads();

  if (tid < 128) {
    int r = tid >> 5, mid = tid & 31;
    float a = db1[mid];
#pragma unroll 8
    for (int k = 0; k < 64; ++k) a = fmaf(x2[r][k], dW1[k * 32 + mid], a);
    h1s[r][mid] = fmaxf(a, 0.f);
  }
  __syncthreads();
  if (tid < 64) {
    int r = tid >> 4, low = tid & 15;
    float a = db2[low];
#pragma unroll
    for (int k = 0; k < 32; ++k) a = fmaf(h1s[r][k], dW2[k * 16 + low], a);
    h2s[r][low] = fmaxf(a, 0.f);
  }
  __syncthreads();
  if (tid < 4) {
    float a = db3[0];
#pragma unroll
    for (int k = 0; k < 16; ++k) a = fmaf(h2s[tid][k], dW3[k], a);
    out[bb * 256 + nbase + tid] = a;
  }
}

}  // namespace

extern "C" void kernel_launch(void* const* d_in, const int* in_sizes, int n_in,
                              void* d_out, int out_size, void* d_ws, size_t ws_size,
                              hipStream_t stream) {
  const float* x_seq = (const float*)d_in[0];
  // d_in[1] = edge_index (unused by reference)
  const float* Wi   = (const float*)d_in[2];
  const float* bi   = (const float*)d_in[3];
  const float* Wqkv = (const float*)d_in[4];
  const float* bqkv = (const float*)d_in[5];
  const float* Wo   = (const float*)d_in[6];
  const float* bo   = (const float*)d_in[7];
  const float* ln1g = (const float*)d_in[8];
  const float* ln1b = (const float*)d_in[9];
  const float* W1   = (const float*)d_in[10];
  const float* b1   = (const float*)d_in[11];
  const float* W2   = (const float*)d_in[12];
  const float* b2   = (const float*)d_in[13];
  const float* ln2g = (const float*)d_in[14];
  const float* ln2b = (const float*)d_in[15];
  const float* dW1  = (const float*)d_in[16];
  const float* db1  = (const float*)d_in[17];
  const float* dW2  = (const float*)d_in[18];
  const float* db2  = (const float*)d_in[19];
  const float* dW3  = (const float*)d_in[20];
  const float* db3  = (const float*)d_in[21];

  float* ws   = (float*)d_ws;  // needs >= 15.1 MB
  float* X    = ws + OFF_X;
  float* QKV  = ws + OFF_QKV;
  float* PM1  = ws + OFF_PM1;
  float* PL1  = ws + OFF_PL1;
  float* PA1  = ws + OFF_PA1;

  k_fused0<<<512, 256, 0, stream>>>(x_seq, Wi, bi, Wqkv, bqkv,
                                    Wo, bo, ln1g, ln1b, W1, b1, W2, b2,
                                    ln2g, ln2b, X, QKV);
  k_attn1<<<128, 256, 0, stream>>>(QKV, PM1, PL1, PA1);
  k_fused1<<<128, 256, 0, stream>>>(PM1, PL1, PA1,
                                    Wo + 4096, bo + 64, ln1g + 64, ln1b + 64,
                                    W1 + 64 * 256, b1 + 256, W2 + 256 * 64, b2 + 64,
                                    ln2g + 64, ln2b + 64, X,
                                    dW1, db1, dW2, db2, dW3, db3, (float*)d_out);
}